// Round 6
// baseline (271.088 us; speedup 1.0000x reference)
//
#include <hip/hip_runtime.h>

#define Bn 4
#define Nn 40
#define NCUBE 64000   // 40^3
#define ROWS 128      // rows per full-kernel tile
#define BPB  500      // full blocks per batch
#define SROWS 64      // rows per sums tile
#define SBPB 1000     // dense-sums blocks per batch
#define MAXV 16384    // valid-row list capacity (>= C(40,3)=9880)
#define CBLK 160      // compact-sums blocks per batch

typedef _Float16 f16;
typedef __attribute__((ext_vector_type(8)))  _Float16 f16x8;
typedef __attribute__((ext_vector_type(4)))  _Float16 f16x4;
typedef __attribute__((ext_vector_type(4)))  float    f32x4;
typedef __attribute__((ext_vector_type(16))) float    f32x16;

// ---------------- workspace layout (bytes) ----------------
// 0      : sums[Bn*128] f32
// 2048   : cnt[Bn] int
// 4096   : vlist[Bn*MAXV] int        (compact tier only)
// WBOFF  : f16 weight A-fragments (offsets below in halfs)
#define OFF_WI1 0
#define OFF_WI2 16384
#define OFF_WE  32768
#define OFF_WO1 49152
#define WB_HALFS 114688
#define WB_BYTES (WB_HALFS*2)
#define WBOFF_COMPACT (4096 + Bn*MAXV*4)   // 266240
#define WBOFF_SMALL   2560

// 16B-granule XOR swizzle for [rows][256]-f16 LDS tiles (f16 units).
__device__ __forceinline__ int swz8(int row, int colg) {
    return row*256 + (((colg & ~7) | ((colg ^ row) & 7)) << 3);
}
__device__ __forceinline__ int swzofs(int row, int col) {  // 8B-aligned accesses
    return swz8(row, col >> 3) + (col & 7);
}

// Weight A-fragment for mfma_f32_32x32x16_f16 with SWAPPED operands
// (arg0 = W-frag): lane l, j=0..7 holds W[kt*16 + 8*(l>>5) + j][nt*32 + (l&31)].
// D then maps: out_col(channel) = nt*32 + (reg&3)+8*(reg>>2)+4*(l>>5),
//              out_row(act row) = rowbase + (l&31).
template<bool PRE>
__device__ __forceinline__ f16x8 load_wfrag(const f16* __restrict__ WF,
                                            const float* __restrict__ W,
                                            int N, int NT, int kt, int nt, int l) {
    if constexpr (PRE) {
        return *(const f16x8*)(WF + ((kt*NT + nt)*64 + l)*8);
    } else {
        const int col = nt*32 + (l & 31);
        const int k0  = kt*16 + 8*(l >> 5);
        f16x8 r;
        #pragma unroll
        for (int j = 0; j < 8; ++j) r[j] = (f16)W[(k0 + j)*N + col];
        return r;
    }
}

// Activation B-fragment: lane l needs act[row = base + (l&31)][k = kt*16 + 8*(l>>5) + j]
// = ds_read_b128 at swz8(base + (l&31), areag + 2*kt + (l>>5)).
__device__ __forceinline__ f16x8 lds_af(const f16* hb, int rowbase, int areag, int kt, int l) {
    return *(const f16x8*)&hb[swz8(rowbase + (l & 31), areag + 2*kt + (l >> 5))];
}

// ---------------------------------------------------------------------------
// One-time weight conversion into A-fragment layout + valid-row compaction.
// Blocks [0,56): prep.  Blocks [56,1056): ballot compaction.
// ---------------------------------------------------------------------------
__global__ __launch_bounds__(256)
void prepcount_kernel(const float* __restrict__ Wi1, const float* __restrict__ Wi2,
                      const float* __restrict__ We,  const float* __restrict__ Wo1,
                      f16* __restrict__ WB, const unsigned char* __restrict__ mask,
                      int* __restrict__ cnt, int* __restrict__ vlist) {
    const int blk = blockIdx.x;
    if (blk < 56) {
        int id = blk*256 + threadIdx.x;   // 0..14335
        const float* W; int NT, N; f16* WF; int fid;
        if (id < 2048)      { W = Wi1; NT = 4; N = 128; WF = WB+OFF_WI1; fid = id; }
        else if (id < 4096) { W = Wi2; NT = 4; N = 128; WF = WB+OFF_WI2; fid = id-2048; }
        else if (id < 6144) { W = We;  NT = 4; N = 128; WF = WB+OFF_WE;  fid = id-4096; }
        else                { W = Wo1; NT = 8; N = 256; WF = WB+OFF_WO1; fid = id-6144; }
        int frag = fid >> 6, l = fid & 63;
        int nt = frag % NT, kt = frag / NT;
        int col = nt*32 + (l & 31), k0 = kt*16 + 8*(l >> 5);
        #pragma unroll
        for (int j = 0; j < 8; ++j) WF[frag*512 + l*8 + j] = (f16)W[(k0 + j)*N + col];
    } else {
        const int idx = (blk - 56)*256 + threadIdx.x;   // 0..255999
        const int b = idx / NCUBE, e = idx % NCUBE;
        const int k = e % Nn, ij = e / Nn, j = ij % Nn, i = ij / Nn;
        const bool v = (i < j) && (j < k) &&
                       mask[b*Nn+i] && mask[b*Nn+j] && mask[b*Nn+k];
        const unsigned long long m = __ballot(v);
        const int lane = threadIdx.x & 63;
        const int c = __popcll(m);
        int base = 0;
        if (lane == 0 && c) base = atomicAdd(&cnt[b], c);
        base = __shfl(base, 0);
        if (v) vlist[b*MAXV + base + __popcll(m & ((1ull<<lane)-1ull))] = e;
    }
}

// ---------------------------------------------------------------------------
// Sums kernel: stages 1-2 + masked exp-sum over 64-row tiles. 8 waves =
// 2 row-groups (wr: 32 rows) x 4 col-slices (wc: 32 chans). 32x32x16 MFMA.
// ---------------------------------------------------------------------------
template<bool PRE, bool COMPACT>
__global__ __launch_bounds__(512, 4)
void sums_kernel(const float* __restrict__ x, const unsigned char* __restrict__ mask,
                 const float* __restrict__ Wi1, const float* __restrict__ bi1,
                 const float* __restrict__ Wi2, const float* __restrict__ bi2,
                 float* __restrict__ sums, const int* __restrict__ cnt,
                 const int* __restrict__ vlist, const f16* __restrict__ WB)
{
    const int tid = threadIdx.x;
    const int l = tid & 63, w = tid >> 6, lr = l & 31, lh = l >> 5;
    const int wr = w >> 2, wc = w & 3;
    int b, r0;
    if (COMPACT) { b = blockIdx.x / CBLK; r0 = (blockIdx.x % CBLK)*SROWS; if (r0 >= cnt[b]) return; }
    else         { b = blockIdx.x / SBPB; r0 = (blockIdx.x % SBPB)*SROWS; }

    __shared__ __align__(16) f16 hb[SROWS*256];
    __shared__ int earr[SROWS];
    __shared__ unsigned char mlds[Nn];
    __shared__ int anyv;

    if (!COMPACT) { if (tid < Nn) mlds[tid] = mask[b*Nn + tid]; if (tid == 0) anyv = 0; }
    if (tid < SROWS) {
        if (COMPACT) { int r = r0 + tid; earr[tid] = (r < cnt[b]) ? vlist[b*MAXV + r] : -1; }
        else earr[tid] = r0 + tid;
    }
    __syncthreads();

    bool rv;
    {
        int e = earr[32*wr + lr];
        if (!COMPACT) {
            int k = e % Nn, ij = e / Nn, j = ij % Nn, i = ij / Nn;
            rv = (i < j) && (j < k) && mlds[i] && mlds[j] && mlds[k];
            if (__any(rv)) anyv = 1;
            __syncthreads();
            if (!anyv) return;
        } else rv = (e >= 0);
    }

    // phase A: gather x rows -> f16 LDS cols [128,256)
    #pragma unroll
    for (int p = 0; p < 2; ++p) {
        const int row = p*32 + (tid >> 4);
        const int c0  = (tid & 15)*8;
        int e = earr[row]; if (e < 0) e = 0;
        const float4 x0 = *(const float4*)&x[((long)(b*NCUBE + e))*128 + c0];
        const float4 x1 = *(const float4*)&x[((long)(b*NCUBE + e))*128 + c0 + 4];
        f16x8 v; v[0]=(f16)x0.x; v[1]=(f16)x0.y; v[2]=(f16)x0.z; v[3]=(f16)x0.w;
                 v[4]=(f16)x1.x; v[5]=(f16)x1.y; v[6]=(f16)x1.z; v[7]=(f16)x1.w;
        *(f16x8*)&hb[swzofs(row, 128 + c0)] = v;   // c0 multiple of 8 -> granule-aligned
    }
    __syncthreads();

    // stage 1: h1 = relu(x @ Wi1 + bi1) -> cols [0,128)
    f32x16 acc;
    #pragma unroll
    for (int rg = 0; rg < 4; ++rg) {
        const float4 bv = *(const float4*)(bi1 + 32*wc + 8*rg + 4*lh);
        acc[rg*4+0]=bv.x; acc[rg*4+1]=bv.y; acc[rg*4+2]=bv.z; acc[rg*4+3]=bv.w;
    }
    #pragma unroll
    for (int kt = 0; kt < 8; ++kt) {
        const f16x8 wf = load_wfrag<PRE>(WB+OFF_WI1, Wi1, 128, 4, kt, wc, l);
        const f16x8 af = lds_af(hb, 32*wr, 16, kt, l);
        acc = __builtin_amdgcn_mfma_f32_32x32x16_f16(wf, af, acc, 0, 0, 0);
    }
    #pragma unroll
    for (int rg = 0; rg < 4; ++rg) {
        f16x4 v;
        #pragma unroll
        for (int q = 0; q < 4; ++q) v[q] = (f16)fmaxf(acc[rg*4+q], 0.f);
        *(f16x4*)&hb[swzofs(32*wr + lr, 32*wc + 8*rg + 4*lh)] = v;
    }
    __syncthreads();

    // stage 2: xf = h1 @ Wi2 + bi2
    #pragma unroll
    for (int rg = 0; rg < 4; ++rg) {
        const float4 bv = *(const float4*)(bi2 + 32*wc + 8*rg + 4*lh);
        acc[rg*4+0]=bv.x; acc[rg*4+1]=bv.y; acc[rg*4+2]=bv.z; acc[rg*4+3]=bv.w;
    }
    #pragma unroll
    for (int kt = 0; kt < 8; ++kt) {
        const f16x8 wf = load_wfrag<PRE>(WB+OFF_WI2, Wi2, 128, 4, kt, wc, l);
        const f16x8 af = lds_af(hb, 32*wr, 0, kt, l);
        acc = __builtin_amdgcn_mfma_f32_32x32x16_f16(wf, af, acc, 0, 0, 0);
    }

    // masked exp-sum; reduce over the 32 rows (l&31), atomics from lr==0 lanes
    float s[16];
    #pragma unroll
    for (int r = 0; r < 16; ++r) s[r] = rv ? __expf(acc[r]) : 0.0f;
    #pragma unroll
    for (int r = 0; r < 16; ++r) {
        float v = s[r];
        v += __shfl_xor(v, 1); v += __shfl_xor(v, 2);
        v += __shfl_xor(v, 4); v += __shfl_xor(v, 8); v += __shfl_xor(v, 16);
        if (lr == 0) atomicAdd(&sums[b*128 + 32*wc + 8*(r>>2) + 4*lh + (r&3)], v);
    }
}

// ---------------------------------------------------------------------------
// Full kernel: all 5 stages over 128-row tiles. 8 waves = 2 row-groups
// (wr: 64 rows as mt-pair of 32) x 4 col-slices (wc: 32 chans s1-3 / 64 s4).
// 32x32x16 MFMA; single f16 [128][256] LDS tile (swizzled):
//   phA: x -> [128,256) | s1: h1 -> [0,128) | s2: xf -> [128,256), acc2 := a
//   s3: a*xi -> [0,128) | s4: K=256 over [a*xi | xf] | s5: 256->1 reduce.
// ---------------------------------------------------------------------------
template<bool PRE>
__global__ __launch_bounds__(512, 4)
void full_kernel(const float* __restrict__ x, const unsigned char* __restrict__ mask,
                 const float* __restrict__ Wi1, const float* __restrict__ bi1,
                 const float* __restrict__ Wi2, const float* __restrict__ bi2,
                 const float* __restrict__ We,
                 const float* __restrict__ Wo1, const float* __restrict__ bo1,
                 const float* __restrict__ Wo2, const float* __restrict__ bo2,
                 const float* __restrict__ sums, const f16* __restrict__ WB,
                 float* __restrict__ out)
{
    const int tid = threadIdx.x;
    const int l = tid & 63, w = tid >> 6, lr = l & 31, lh = l >> 5;
    const int wr = w >> 2, wc = w & 3;
    const int b = blockIdx.x / BPB;
    const int e0 = (blockIdx.x % BPB) * ROWS;

    __shared__ __align__(16) f16 hb[ROWS*256];   // 64 KB
    __shared__ float red[8][64];
    __shared__ unsigned char mlds[Nn];

    if (tid < Nn) mlds[tid] = mask[b*Nn + tid];

    // phase A: x tile -> f16 LDS cols [128,256)
    #pragma unroll
    for (int p = 0; p < 4; ++p) {
        const int row = p*32 + (tid >> 4);
        const int c0  = (tid & 15)*8;
        const long base = ((long)(b*NCUBE + e0 + row))*128 + c0;
        const float4 x0 = *(const float4*)&x[base];
        const float4 x1 = *(const float4*)&x[base + 4];
        f16x8 v; v[0]=(f16)x0.x; v[1]=(f16)x0.y; v[2]=(f16)x0.z; v[3]=(f16)x0.w;
                 v[4]=(f16)x1.x; v[5]=(f16)x1.y; v[6]=(f16)x1.z; v[7]=(f16)x1.w;
        *(f16x8*)&hb[swzofs(row, 128 + c0)] = v;
    }
    __syncthreads();

    bool valid[2];
    #pragma unroll
    for (int mt = 0; mt < 2; ++mt) {
        int e = e0 + 64*wr + 32*mt + lr;
        int k = e % Nn, ij = e / Nn, j = ij % Nn, i = ij / Nn;
        valid[mt] = (i < j) && (j < k) && mlds[i] && mlds[j] && mlds[k];
    }

    // ---- stage 1: h1 = relu(x @ Wi1 + bi1) -> cols [0,128) ----
    {
        f32x16 acc1[2];
        #pragma unroll
        for (int rg = 0; rg < 4; ++rg) {
            const float4 bv = *(const float4*)(bi1 + 32*wc + 8*rg + 4*lh);
            #pragma unroll
            for (int mt = 0; mt < 2; ++mt) {
                acc1[mt][rg*4+0]=bv.x; acc1[mt][rg*4+1]=bv.y;
                acc1[mt][rg*4+2]=bv.z; acc1[mt][rg*4+3]=bv.w;
            }
        }
        #pragma unroll
        for (int kt = 0; kt < 8; ++kt) {
            const f16x8 wf = load_wfrag<PRE>(WB+OFF_WI1, Wi1, 128, 4, kt, wc, l);
            #pragma unroll
            for (int mt = 0; mt < 2; ++mt) {
                const f16x8 af = lds_af(hb, 64*wr + 32*mt, 16, kt, l);
                acc1[mt] = __builtin_amdgcn_mfma_f32_32x32x16_f16(wf, af, acc1[mt], 0, 0, 0);
            }
        }
        #pragma unroll
        for (int mt = 0; mt < 2; ++mt)
            #pragma unroll
            for (int rg = 0; rg < 4; ++rg) {
                f16x4 v;
                #pragma unroll
                for (int q = 0; q < 4; ++q) v[q] = (f16)fmaxf(acc1[mt][rg*4+q], 0.f);
                *(f16x4*)&hb[swzofs(64*wr + 32*mt + lr, 32*wc + 8*rg + 4*lh)] = v;
            }
    }
    __syncthreads();

    // ---- stage 2: xf = h1 @ Wi2 + bi2 -> [128,256); acc2 := a in place ----
    f32x16 acc2[2];
    {
        #pragma unroll
        for (int rg = 0; rg < 4; ++rg) {
            const float4 bv = *(const float4*)(bi2 + 32*wc + 8*rg + 4*lh);
            #pragma unroll
            for (int mt = 0; mt < 2; ++mt) {
                acc2[mt][rg*4+0]=bv.x; acc2[mt][rg*4+1]=bv.y;
                acc2[mt][rg*4+2]=bv.z; acc2[mt][rg*4+3]=bv.w;
            }
        }
        #pragma unroll
        for (int kt = 0; kt < 8; ++kt) {
            const f16x8 wf = load_wfrag<PRE>(WB+OFF_WI2, Wi2, 128, 4, kt, wc, l);
            #pragma unroll
            for (int mt = 0; mt < 2; ++mt) {
                const f16x8 af = lds_af(hb, 64*wr + 32*mt, 0, kt, l);
                acc2[mt] = __builtin_amdgcn_mfma_f32_32x32x16_f16(wf, af, acc2[mt], 0, 0, 0);
            }
        }
        // x region dead after s1's barrier: write xf there.
        #pragma unroll
        for (int mt = 0; mt < 2; ++mt)
            #pragma unroll
            for (int rg = 0; rg < 4; ++rg) {
                f16x4 v;
                #pragma unroll
                for (int q = 0; q < 4; ++q) v[q] = (f16)acc2[mt][rg*4+q];
                *(f16x4*)&hb[swzofs(64*wr + 32*mt + lr, 128 + 32*wc + 8*rg + 4*lh)] = v;
            }
        // convert acc2 in place to softmax weight a
        #pragma unroll
        for (int rg = 0; rg < 4; ++rg) {
            const float4 sv = *(const float4*)(sums + b*128 + 32*wc + 8*rg + 4*lh);
            const float rinv[4] = {1.f/sv.x, 1.f/sv.y, 1.f/sv.z, 1.f/sv.w};
            #pragma unroll
            for (int mt = 0; mt < 2; ++mt)
                #pragma unroll
                for (int q = 0; q < 4; ++q)
                    acc2[mt][rg*4+q] = valid[mt] ? __expf(acc2[mt][rg*4+q]) * rinv[q] : 0.0f;
        }
    }
    __syncthreads();

    // ---- stage 3: xi = relu(xf @ We); a*xi -> cols [0,128) ----
    {
        f32x16 acc3[2];
        #pragma unroll
        for (int mt = 0; mt < 2; ++mt)
            #pragma unroll
            for (int r = 0; r < 16; ++r) acc3[mt][r] = 0.f;
        #pragma unroll
        for (int kt = 0; kt < 8; ++kt) {
            const f16x8 wf = load_wfrag<PRE>(WB+OFF_WE, We, 128, 4, kt, wc, l);
            #pragma unroll
            for (int mt = 0; mt < 2; ++mt) {
                const f16x8 af = lds_af(hb, 64*wr + 32*mt, 16, kt, l);
                acc3[mt] = __builtin_amdgcn_mfma_f32_32x32x16_f16(wf, af, acc3[mt], 0, 0, 0);
            }
        }
        #pragma unroll
        for (int mt = 0; mt < 2; ++mt)
            #pragma unroll
            for (int rg = 0; rg < 4; ++rg) {
                f16x4 v;
                #pragma unroll
                for (int q = 0; q < 4; ++q)
                    v[q] = (f16)(acc2[mt][rg*4+q] * fmaxf(acc3[mt][rg*4+q], 0.f));
                *(f16x4*)&hb[swzofs(64*wr + 32*mt + lr, 32*wc + 8*rg + 4*lh)] = v;
            }
    }
    __syncthreads();

    // ---- stage 4: g = relu(h @ Wo1 + bo1), K=256 over h=[a*xi | xf] ----
    f32x16 acc4[2][2];   // [mt][ntl], chans 64*wc + 32*ntl + ...
    #pragma unroll
    for (int ntl = 0; ntl < 2; ++ntl)
        #pragma unroll
        for (int rg = 0; rg < 4; ++rg) {
            const float4 bv = *(const float4*)(bo1 + 64*wc + 32*ntl + 8*rg + 4*lh);
            #pragma unroll
            for (int mt = 0; mt < 2; ++mt) {
                acc4[mt][ntl][rg*4+0]=bv.x; acc4[mt][ntl][rg*4+1]=bv.y;
                acc4[mt][ntl][rg*4+2]=bv.z; acc4[mt][ntl][rg*4+3]=bv.w;
            }
        }
    #pragma unroll
    for (int kt = 0; kt < 16; ++kt) {
        f16x8 of0 = load_wfrag<PRE>(WB+OFF_WO1, Wo1, 256, 8, kt, 2*wc+0, l);
        f16x8 of1 = load_wfrag<PRE>(WB+OFF_WO1, Wo1, 256, 8, kt, 2*wc+1, l);
        #pragma unroll
        for (int mt = 0; mt < 2; ++mt) {
            const f16x8 af = lds_af(hb, 64*wr + 32*mt, 0, kt, l);
            acc4[mt][0] = __builtin_amdgcn_mfma_f32_32x32x16_f16(of0, af, acc4[mt][0], 0, 0, 0);
            acc4[mt][1] = __builtin_amdgcn_mfma_f32_32x32x16_f16(of1, af, acc4[mt][1], 0, 0, 0);
        }
    }

    // ---- stage 5: out = relu(g) @ Wo2 + bo2, reduce 256 -> 1 per row ----
    {
        float outp[2] = {0.f, 0.f};
        #pragma unroll
        for (int ntl = 0; ntl < 2; ++ntl)
            #pragma unroll
            for (int rg = 0; rg < 4; ++rg) {
                const float4 wv = *(const float4*)(Wo2 + 64*wc + 32*ntl + 8*rg + 4*lh);
                #pragma unroll
                for (int mt = 0; mt < 2; ++mt) {
                    outp[mt] += fmaxf(acc4[mt][ntl][rg*4+0], 0.f)*wv.x
                              + fmaxf(acc4[mt][ntl][rg*4+1], 0.f)*wv.y
                              + fmaxf(acc4[mt][ntl][rg*4+2], 0.f)*wv.z
                              + fmaxf(acc4[mt][ntl][rg*4+3], 0.f)*wv.w;
                }
            }
        #pragma unroll
        for (int mt = 0; mt < 2; ++mt) outp[mt] += __shfl_xor(outp[mt], 32);
        if (l < 32) {
            red[w][lr]      = outp[0];
            red[w][32 + lr] = outp[1];
        }
        __syncthreads();
        if (tid < ROWS) {
            const int wr2 = tid >> 6, idx = tid & 63;
            out[(long)b*NCUBE + e0 + tid] =
                red[wr2*4+0][idx] + red[wr2*4+1][idx] +
                red[wr2*4+2][idx] + red[wr2*4+3][idx] + bo2[0];
        }
    }
}

extern "C" void kernel_launch(void* const* d_in, const int* in_sizes, int n_in,
                              void* d_out, int out_size, void* d_ws, size_t ws_size,
                              hipStream_t stream) {
    const float*         x    = (const float*)d_in[0];
    const unsigned char* mask = (const unsigned char*)d_in[1];
    const float* Wi1 = (const float*)d_in[2];
    const float* bi1 = (const float*)d_in[3];
    const float* Wi2 = (const float*)d_in[4];
    const float* bi2 = (const float*)d_in[5];
    const float* We  = (const float*)d_in[6];
    const float* Wo1 = (const float*)d_in[7];
    const float* bo1 = (const float*)d_in[8];
    const float* Wo2 = (const float*)d_in[9];
    const float* bo2 = (const float*)d_in[10];
    float* out  = (float*)d_out;
    float* sums = (float*)d_ws;
    int*   cnt   = (int*)((char*)d_ws + 2048);
    int*   vlist = (int*)((char*)d_ws + 4096);

    const bool compact = ws_size >= (size_t)(WBOFF_COMPACT + WB_BYTES);
    const size_t wboff = compact ? WBOFF_COMPACT : WBOFF_SMALL;
    const bool pre     = ws_size >= wboff + WB_BYTES;
    f16* WB = (f16*)((char*)d_ws + wboff);

    hipMemsetAsync(d_ws, 0, 2048 + Bn*sizeof(int), stream);

    if (compact) {
        prepcount_kernel<<<1056, 256, 0, stream>>>(Wi1, Wi2, We, Wo1, WB, mask, cnt, vlist);
        sums_kernel<true, true><<<Bn*CBLK, 512, 0, stream>>>(x, mask, Wi1, bi1, Wi2, bi2,
                                                             sums, cnt, vlist, WB);
        full_kernel<true><<<Bn*BPB, 512, 0, stream>>>(x, mask, Wi1, bi1, Wi2, bi2, We,
                                                      Wo1, bo1, Wo2, bo2, sums, WB, out);
    } else if (pre) {
        prepcount_kernel<<<56, 256, 0, stream>>>(Wi1, Wi2, We, Wo1, WB, mask, cnt, vlist);
        sums_kernel<true, false><<<Bn*SBPB, 512, 0, stream>>>(x, mask, Wi1, bi1, Wi2, bi2,
                                                              sums, cnt, vlist, WB);
        full_kernel<true><<<Bn*BPB, 512, 0, stream>>>(x, mask, Wi1, bi1, Wi2, bi2, We,
                                                      Wo1, bo1, Wo2, bo2, sums, WB, out);
    } else {
        sums_kernel<false, false><<<Bn*SBPB, 512, 0, stream>>>(x, mask, Wi1, bi1, Wi2, bi2,
                                                               sums, cnt, vlist, WB);
        full_kernel<false><<<Bn*BPB, 512, 0, stream>>>(x, mask, Wi1, bi1, Wi2, bi2, We,
                                                       Wo1, bo1, Wo2, bo2, sums, WB, out);
    }
}